// Round 4
// baseline (435.606 us; speedup 1.0000x reference)
//
#include <hip/hip_runtime.h>
#include <hip/hip_bf16.h>

// B=16, N=2048, D=64 scaled-dot-product attention, fp32 in/out.
// Outputs concatenated: out [B,N,D] then attn_weights [B,N,N].
//
// R4: R3 layouts (Vt swizzle, Pf, float4 attn stores) kept bit-identical.
// Changes: native bf16 casts (compiler packs v_cvt_pk_bf16_f32), sweep-1
// LDS-free with register dbuf (K direct global->reg, L1-served), sweep-2
// LDS double-buffer (1 barrier/tile) + depth-1 register prefetch,
// launch_bounds(256,2) to match the grid-limited 2 blocks/CU.
#define B_  16
#define N_  2048
#define D_  64
#define KT  64            // key tile (sweep 2)
#define NTILES (N_ / KT)  // 32
// scale * log2(e) = (1/8) * 1.4426950408889634
#define SCALE_LOG2 0.18033688011112042f

typedef __attribute__((ext_vector_type(8))) short  frag8;   // 8 bf16 (4 VGPRs)
typedef __attribute__((ext_vector_type(4))) float  floatx4; // 4 fp32 acc

union FragU { frag8 fr; unsigned short us[8]; };

__device__ __forceinline__ unsigned short f2bf(float f) {
    // native cast: compiler fuses adjacent pairs into v_cvt_pk_bf16_f32
    return __builtin_bit_cast(unsigned short, __float2bfloat16(f));
}
__device__ __forceinline__ float exp2fast(float x) {
    return __builtin_amdgcn_exp2f(x);   // v_exp_f32; args are O(+-30), safe
}

struct __align__(16) SMem {
    unsigned short Ks[2][64][72];   // K tile bf16, double-buffered
    unsigned short Vt[2][64][72];   // V^T tile bf16 [dim][key ^ swz], dbuf
    float          Pf[4][16][68];   // per-wave normalized P fp32
};

__global__ __launch_bounds__(256, 2) void attn_fused(
    const float* __restrict__ Q, const float* __restrict__ K,
    const float* __restrict__ V, float* __restrict__ out,
    float* __restrict__ attn)
{
    __shared__ SMem sm;

    const int qtile = blockIdx.x;   // 0..31
    const int b     = blockIdx.y;   // 0..15
    const int qbase = qtile * 64;
    const int tid   = threadIdx.x;
    const int w     = tid >> 6;     // wave 0..3 -> Q rows [16w,16w+16)
    const int lane  = tid & 63;
    const int lm    = lane & 15;
    const int quad  = lane >> 4;
    const int q8    = quad * 8;
    const size_t bN = (size_t)b * N_;

    const int srow = tid >> 2;          // staging: row 0..63
    const int sc0  = (tid & 3) * 16;    // staging: col base {0,16,32,48}
    const int vswz = srow ^ (((sc0 >> 4) & 3) << 3);   // Vt bank swizzle

    // ---- Q frags: wave-private rows, direct global->reg ----
    FragU aq0, aq1;
    {
        const float* qp = Q + (bN + qbase + w*16 + lm) * D_;
        float4 f0 = *(const float4*)(qp + q8);
        float4 f1 = *(const float4*)(qp + q8 + 4);
        float4 f2 = *(const float4*)(qp + 32 + q8);
        float4 f3 = *(const float4*)(qp + 36 + q8);
        #pragma unroll
        for (int j = 0; j < 4; ++j) {
            aq0.us[j]   = f2bf(f0[j]);  aq0.us[4+j] = f2bf(f1[j]);
            aq1.us[j]   = f2bf(f2[j]);  aq1.us[4+j] = f2bf(f3[j]);
        }
    }

    // ================= sweep 1: exp-sums, LDS-free, reg-dbuf ===============
    // Per 32-key step: K B-frags direct from global (keys kb+ns*16+lm, dims
    // q8-based). All 4 waves read identical addresses -> L1-served.
    float s4[4] = {0.f, 0.f, 0.f, 0.f};

    float4 kA[8], kB[8];
    auto loadKd = [&](float4* kf, int kb) {
        #pragma unroll
        for (int ns = 0; ns < 2; ++ns) {
            const float* base = K + (bN + kb + ns*16 + lm) * D_;
            kf[ns*4+0] = *(const float4*)(base + q8);
            kf[ns*4+1] = *(const float4*)(base + q8 + 4);
            kf[ns*4+2] = *(const float4*)(base + 32 + q8);
            kf[ns*4+3] = *(const float4*)(base + 36 + q8);
        }
    };
    auto qkStep = [&](const float4* kf) {
        #pragma unroll
        for (int ns = 0; ns < 2; ++ns) {
            FragU c0, c1;
            #pragma unroll
            for (int j = 0; j < 4; ++j) {
                c0.us[j]   = f2bf(kf[ns*4+0][j]);
                c0.us[4+j] = f2bf(kf[ns*4+1][j]);
                c1.us[j]   = f2bf(kf[ns*4+2][j]);
                c1.us[4+j] = f2bf(kf[ns*4+3][j]);
            }
            floatx4 a = {0.f, 0.f, 0.f, 0.f};
            a = __builtin_amdgcn_mfma_f32_16x16x32_bf16(aq0.fr, c0.fr, a, 0, 0, 0);
            a = __builtin_amdgcn_mfma_f32_16x16x32_bf16(aq1.fr, c1.fr, a, 0, 0, 0);
            #pragma unroll
            for (int r = 0; r < 4; ++r)
                s4[r] += exp2fast(a[r] * SCALE_LOG2);
        }
    };

    loadKd(kA, 0);
    for (int t = 0; t < 64; t += 2) {        // 64 steps x 32 keys
        if (t + 1 < 64) loadKd(kB, (t+1)*32);
        qkStep(kA);
        if (t + 2 < 64) loadKd(kA, (t+2)*32);
        qkStep(kB);
    }

    // one cross-lane reduce for the whole sweep (16 lm lanes per quad)
    float invl[4];
    #pragma unroll
    for (int r = 0; r < 4; ++r) {
        float v = s4[r];
        #pragma unroll
        for (int off = 1; off < 16; off <<= 1)
            v += __shfl_xor(v, off, 64);
        invl[r] = 1.0f / v;
    }

    floatx4 oacc[4];
    #pragma unroll
    for (int ns = 0; ns < 4; ++ns) oacc[ns] = (floatx4){0.f, 0.f, 0.f, 0.f};

    // attn store lane mapping: 8 rows x 128B-contiguous per instruction
    const int prow = lane >> 3;        // 0..7
    const int pcol = (lane & 7) * 4;   // 0,4,...,28

    // ========== sweep 2: recompute S, write attn, accumulate O=PV ==========
    float4 fk[4], fv[4];
    auto loadS = [&](int t) {
        const float4* srcK = (const float4*)(K + (bN + t*KT + srow) * D_ + sc0);
        const float4* srcV = (const float4*)(V + (bN + t*KT + srow) * D_ + sc0);
        #pragma unroll
        for (int i = 0; i < 4; ++i) fk[i] = srcK[i];
        #pragma unroll
        for (int i = 0; i < 4; ++i) fv[i] = srcV[i];
    };
    auto writeS = [&](int buf) {
        #pragma unroll
        for (int i = 0; i < 4; ++i) {
            ushort4 u; u.x=f2bf(fk[i].x); u.y=f2bf(fk[i].y);
                       u.z=f2bf(fk[i].z); u.w=f2bf(fk[i].w);
            *(ushort4*)&sm.Ks[buf][srow][sc0 + i*4] = u;
        }
        #pragma unroll
        for (int i = 0; i < 4; ++i) {   // V transposed: Vt[dim][key^swz]
            sm.Vt[buf][sc0 + i*4 + 0][vswz] = f2bf(fv[i].x);
            sm.Vt[buf][sc0 + i*4 + 1][vswz] = f2bf(fv[i].y);
            sm.Vt[buf][sc0 + i*4 + 2][vswz] = f2bf(fv[i].z);
            sm.Vt[buf][sc0 + i*4 + 3][vswz] = f2bf(fv[i].w);
        }
    };

    loadS(0);
    writeS(0);
    __syncthreads();                   // buf0 visible to all waves

    for (int t = 0; t < NTILES; ++t) {
        const int cur = t & 1;
        if (t + 1 < NTILES) loadS(t + 1);   // issue early; hide under compute

        // QK^T from Ks[cur]
        floatx4 acc[4];
        #pragma unroll
        for (int ns = 0; ns < 4; ++ns) {
            frag8 b0 = *(const frag8*)&sm.Ks[cur][ns*16 + lm][q8];
            frag8 b1 = *(const frag8*)&sm.Ks[cur][ns*16 + lm][32 + q8];
            floatx4 a = {0.f, 0.f, 0.f, 0.f};
            a = __builtin_amdgcn_mfma_f32_16x16x32_bf16(aq0.fr, b0, a, 0, 0, 0);
            a = __builtin_amdgcn_mfma_f32_16x16x32_bf16(aq1.fr, b1, a, 0, 0, 0);
            acc[ns] = a;
        }

        // normalized P -> wave-private fp32 LDS (C layout)
        #pragma unroll
        for (int ns = 0; ns < 4; ++ns)
            #pragma unroll
            for (int r = 0; r < 4; ++r)
                sm.Pf[w][quad*4 + r][ns*16 + lm] =
                    exp2fast(acc[ns][r] * SCALE_LOG2) * invl[r];

        // attn: 4 x 128B-contiguous float4 stores per wave-tile
        // (in-wave LDS write->read, lgkmcnt ordering; no barrier needed)
        #pragma unroll
        for (int rg = 0; rg < 2; ++rg)
            #pragma unroll
            for (int half = 0; half < 2; ++half) {
                float4 pv = *(const float4*)&sm.Pf[w][rg*8 + prow][half*32 + pcol];
                *(float4*)&attn[(bN + qbase + w*16 + rg*8 + prow) * N_
                                + t*KT + half*32 + pcol] = pv;
            }

        // P A-frags: read fp32 rows from Pf, convert to bf16
        FragU pa0, pa1;
        {
            float4 p0 = *(const float4*)&sm.Pf[w][lm][q8];
            float4 p1 = *(const float4*)&sm.Pf[w][lm][q8 + 4];
            float4 p2 = *(const float4*)&sm.Pf[w][lm][32 + q8];
            float4 p3 = *(const float4*)&sm.Pf[w][lm][36 + q8];
            #pragma unroll
            for (int j = 0; j < 4; ++j) {
                pa0.us[j]   = f2bf(p0[j]);  pa0.us[4+j] = f2bf(p1[j]);
                pa1.us[j]   = f2bf(p2[j]);  pa1.us[4+j] = f2bf(p3[j]);
            }
        }

        // PV accumulate (Vt read un-swizzles: key block q8 ^ (dg<<3))
        #pragma unroll
        for (int dg = 0; dg < 4; ++dg) {
            const int kb = q8 ^ (dg << 3);
            frag8 v0 = *(const frag8*)&sm.Vt[cur][dg*16 + lm][kb];
            frag8 v1 = *(const frag8*)&sm.Vt[cur][dg*16 + lm][32 + kb];
            oacc[dg] = __builtin_amdgcn_mfma_f32_16x16x32_bf16(pa0.fr, v0, oacc[dg], 0, 0, 0);
            oacc[dg] = __builtin_amdgcn_mfma_f32_16x16x32_bf16(pa1.fr, v1, oacc[dg], 0, 0, 0);
        }

        // stage tile t+1 into the other buffer (loads drain here, after
        // the long compute above), then one barrier per tile
        if (t + 1 < NTILES) writeS(cur ^ 1);
        __syncthreads();
    }

    // ---- write O [B,N,D] ----
    #pragma unroll
    for (int dg = 0; dg < 4; ++dg)
        #pragma unroll
        for (int r = 0; r < 4; ++r)
            out[(bN + qbase + w*16 + quad*4 + r) * D_ + dg*16 + lm] = oacc[dg][r];
}

extern "C" void kernel_launch(void* const* d_in, const int* in_sizes, int n_in,
                              void* d_out, int out_size, void* d_ws, size_t ws_size,
                              hipStream_t stream) {
    const float* Q = (const float*)d_in[0];
    const float* K = (const float*)d_in[1];
    const float* V = (const float*)d_in[2];
    float* out  = (float*)d_out;
    float* attn = out + (size_t)B_ * N_ * D_;   // tuple order: out, attn_weights
    dim3 grid(NTILES, B_);   // 32 x 16 = 512 blocks
    attn_fused<<<grid, 256, 0, stream>>>(Q, K, V, out, attn);
}

// Round 5
// 366.223 us; speedup vs baseline: 1.1895x; 1.1895x over previous
//
#include <hip/hip_runtime.h>
#include <hip/hip_bf16.h>

// B=16, N=2048, D=64 scaled-dot-product attention, fp32 in/out.
// Outputs concatenated: out [B,N,D] then attn_weights [B,N,N].
//
// R5: two-kernel key-split for occupancy.
//   memset(ws, out) -> denom_kernel (grid 2048, key-quarters, atomicAdd sums)
//                   -> attn_kernel  (grid 1024, key-halves, atomicAdd O)
// Both use XCD-aware block swizzle (each XCD owns 2 batches -> K/V L2-fit).
#define B_  16
#define N_  2048
#define D_  64
// scale * log2(e) = (1/8) * 1.4426950408889634
#define SCALE_LOG2 0.18033688011112042f

typedef __attribute__((ext_vector_type(8))) short  frag8;   // 8 bf16 (4 VGPRs)
typedef __attribute__((ext_vector_type(4))) float  floatx4; // 4 fp32 acc

union FragU { frag8 fr; unsigned short us[8]; };

__device__ __forceinline__ unsigned short f2bf(float f) {
    // native cast: compiler packs pairs into v_cvt_pk_bf16_f32
    return __builtin_bit_cast(unsigned short, __float2bfloat16(f));
}
__device__ __forceinline__ float exp2fast(float x) {
    return __builtin_amdgcn_exp2f(x);   // args O(+-30), safe
}

// ======================= kernel A: denominators ==========================
// grid 2048 = 8 xcd * (2 b * 32 qtile * 4 kquarter). Each block: 64 Q rows
// x 512 keys, partial exp-sums -> atomicAdd ws[b][row].
__global__ __launch_bounds__(256) void denom_kernel(
    const float* __restrict__ Q, const float* __restrict__ K,
    float* __restrict__ ws)
{
    __shared__ unsigned short Ks[64][72];

    const int id    = blockIdx.x;
    const int xcd   = id & 7;
    const int s     = id >> 3;            // 0..255
    const int b     = xcd * 2 + (s >> 7); // xcd owns batches {2x, 2x+1}
    const int rem   = s & 127;
    const int qtile = rem >> 2;           // 0..31
    const int kq    = rem & 3;            // 0..3
    const int qbase = qtile * 64;
    const int kbase = kq * 512;
    const size_t bN = (size_t)b * N_;

    const int tid  = threadIdx.x;
    const int w    = tid >> 6;
    const int lane = tid & 63;
    const int lm   = lane & 15;
    const int quad = lane >> 4;
    const int q8   = quad * 8;
    const int srow = tid >> 2;
    const int sc0  = (tid & 3) * 16;

    // Q frags: wave-private rows, direct global->reg
    FragU aq0, aq1;
    {
        const float* qp = Q + (bN + qbase + w*16 + lm) * D_;
        float4 f0 = *(const float4*)(qp + q8);
        float4 f1 = *(const float4*)(qp + q8 + 4);
        float4 f2 = *(const float4*)(qp + 32 + q8);
        float4 f3 = *(const float4*)(qp + 36 + q8);
        #pragma unroll
        for (int j = 0; j < 4; ++j) {
            aq0.us[j]   = f2bf(f0[j]);  aq0.us[4+j] = f2bf(f1[j]);
            aq1.us[j]   = f2bf(f2[j]);  aq1.us[4+j] = f2bf(f3[j]);
        }
    }

    float s4[4] = {0.f, 0.f, 0.f, 0.f};

    ushort4 kreg[4];
    {
        const float4* src = (const float4*)(K + (bN + kbase + srow) * D_ + sc0);
        #pragma unroll
        for (int i = 0; i < 4; ++i) {
            float4 f = src[i];
            kreg[i].x=f2bf(f.x); kreg[i].y=f2bf(f.y);
            kreg[i].z=f2bf(f.z); kreg[i].w=f2bf(f.w);
        }
    }

    for (int t = 0; t < 8; ++t) {          // 8 tiles x 64 keys = 512
        __syncthreads();
        #pragma unroll
        for (int i = 0; i < 4; ++i)
            *(ushort4*)&Ks[srow][sc0 + i*4] = kreg[i];
        __syncthreads();

        float4 fnext[4];
        if (t + 1 < 8) {
            const float4* src = (const float4*)(K + (bN + kbase + (t+1)*64 + srow) * D_ + sc0);
            #pragma unroll
            for (int i = 0; i < 4; ++i) fnext[i] = src[i];
        }

        #pragma unroll
        for (int ns = 0; ns < 4; ++ns) {
            frag8 b0 = *(const frag8*)&Ks[ns*16 + lm][q8];
            frag8 b1 = *(const frag8*)&Ks[ns*16 + lm][32 + q8];
            floatx4 a = {0.f, 0.f, 0.f, 0.f};
            a = __builtin_amdgcn_mfma_f32_16x16x32_bf16(aq0.fr, b0, a, 0, 0, 0);
            a = __builtin_amdgcn_mfma_f32_16x16x32_bf16(aq1.fr, b1, a, 0, 0, 0);
            #pragma unroll
            for (int r = 0; r < 4; ++r)
                s4[r] += exp2fast(a[r] * SCALE_LOG2);
        }

        if (t + 1 < 8) {
            #pragma unroll
            for (int i = 0; i < 4; ++i) {
                kreg[i].x=f2bf(fnext[i].x); kreg[i].y=f2bf(fnext[i].y);
                kreg[i].z=f2bf(fnext[i].z); kreg[i].w=f2bf(fnext[i].w);
            }
        }
    }

    // reduce over the 16 lm lanes, then one atomic per (quad,row)
    #pragma unroll
    for (int r = 0; r < 4; ++r) {
        float v = s4[r];
        #pragma unroll
        for (int off = 1; off < 16; off <<= 1)
            v += __shfl_xor(v, off, 64);
        if (lm == 0)
            atomicAdd(&ws[bN + qbase + w*16 + quad*4 + r], v);
    }
}

// ======================= kernel B: attn + O ==============================
// grid 1024 = 8 xcd * (2 b * 32 qtile * 2 khalf). Each block: 64 Q rows x
// 1024 keys (16 tiles). LDS 35.8KB -> 4 blocks/CU -> 16 waves/CU.
struct __align__(16) SMemB {
    unsigned short Ks[64][72];   // K tile bf16
    unsigned short Vt[64][72];   // V^T tile bf16 [dim][key ^ swz]
    float          Pf[4][16][68];// per-wave normalized P fp32
};

__global__ __launch_bounds__(256, 4) void attn_kernel(
    const float* __restrict__ Q, const float* __restrict__ K,
    const float* __restrict__ V, const float* __restrict__ ws,
    float* __restrict__ out, float* __restrict__ attn)
{
    __shared__ SMemB sm;

    const int id    = blockIdx.x;
    const int xcd   = id & 7;
    const int s     = id >> 3;            // 0..127
    const int b     = xcd * 2 + (s >> 6);
    const int rem   = s & 63;
    const int qtile = rem >> 1;           // 0..31
    const int kh    = rem & 1;            // key half
    const int qbase = qtile * 64;
    const int kbase = kh * 1024;
    const size_t bN = (size_t)b * N_;

    const int tid  = threadIdx.x;
    const int w    = tid >> 6;
    const int lane = tid & 63;
    const int lm   = lane & 15;
    const int quad = lane >> 4;
    const int q8   = quad * 8;
    const int srow = tid >> 2;
    const int sc0  = (tid & 3) * 16;
    const int vswz = srow ^ (((sc0 >> 4) & 3) << 3);   // Vt bank swizzle

    // Q frags
    FragU aq0, aq1;
    {
        const float* qp = Q + (bN + qbase + w*16 + lm) * D_;
        float4 f0 = *(const float4*)(qp + q8);
        float4 f1 = *(const float4*)(qp + q8 + 4);
        float4 f2 = *(const float4*)(qp + 32 + q8);
        float4 f3 = *(const float4*)(qp + 36 + q8);
        #pragma unroll
        for (int j = 0; j < 4; ++j) {
            aq0.us[j]   = f2bf(f0[j]);  aq0.us[4+j] = f2bf(f1[j]);
            aq1.us[j]   = f2bf(f2[j]);  aq1.us[4+j] = f2bf(f3[j]);
        }
    }

    // denominators (complete: kernel A finished before we launched)
    float invl[4];
    #pragma unroll
    for (int r = 0; r < 4; ++r)
        invl[r] = 1.0f / ws[bN + qbase + w*16 + quad*4 + r];

    floatx4 oacc[4];
    #pragma unroll
    for (int dg = 0; dg < 4; ++dg) oacc[dg] = (floatx4){0.f, 0.f, 0.f, 0.f};

    const int prow = lane >> 3;        // attn store: 8 rows x 128B
    const int pcol = (lane & 7) * 4;

    float4 fk[4], fv[4];
    auto loadS = [&](int t) {
        const float4* srcK = (const float4*)(K + (bN + kbase + t*64 + srow) * D_ + sc0);
        const float4* srcV = (const float4*)(V + (bN + kbase + t*64 + srow) * D_ + sc0);
        #pragma unroll
        for (int i = 0; i < 4; ++i) fk[i] = srcK[i];
        #pragma unroll
        for (int i = 0; i < 4; ++i) fv[i] = srcV[i];
    };

    loadS(0);
    for (int t = 0; t < 16; ++t) {
        __syncthreads();   // previous tile consumed
        #pragma unroll
        for (int i = 0; i < 4; ++i) {
            ushort4 u; u.x=f2bf(fk[i].x); u.y=f2bf(fk[i].y);
                       u.z=f2bf(fk[i].z); u.w=f2bf(fk[i].w);
            *(ushort4*)&sm.Ks[srow][sc0 + i*4] = u;
        }
        #pragma unroll
        for (int i = 0; i < 4; ++i) {   // V transposed: Vt[dim][key^swz]
            sm.Vt[sc0 + i*4 + 0][vswz] = f2bf(fv[i].x);
            sm.Vt[sc0 + i*4 + 1][vswz] = f2bf(fv[i].y);
            sm.Vt[sc0 + i*4 + 2][vswz] = f2bf(fv[i].z);
            sm.Vt[sc0 + i*4 + 3][vswz] = f2bf(fv[i].w);
        }
        __syncthreads();   // tile t visible

        if (t + 1 < 16) loadS(t + 1);   // in flight under compute

        // QK^T
        floatx4 acc[4];
        #pragma unroll
        for (int ns = 0; ns < 4; ++ns) {
            frag8 b0 = *(const frag8*)&sm.Ks[ns*16 + lm][q8];
            frag8 b1 = *(const frag8*)&sm.Ks[ns*16 + lm][32 + q8];
            floatx4 a = {0.f, 0.f, 0.f, 0.f};
            a = __builtin_amdgcn_mfma_f32_16x16x32_bf16(aq0.fr, b0, a, 0, 0, 0);
            a = __builtin_amdgcn_mfma_f32_16x16x32_bf16(aq1.fr, b1, a, 0, 0, 0);
            acc[ns] = a;
        }

        // normalized P -> wave-private fp32 LDS
        #pragma unroll
        for (int ns = 0; ns < 4; ++ns)
            #pragma unroll
            for (int r = 0; r < 4; ++r)
                sm.Pf[w][quad*4 + r][ns*16 + lm] =
                    exp2fast(acc[ns][r] * SCALE_LOG2) * invl[r];

        // attn: 4 x 128B-contiguous float4 stores per wave-tile
        #pragma unroll
        for (int rg = 0; rg < 2; ++rg)
            #pragma unroll
            for (int half = 0; half < 2; ++half) {
                float4 pv = *(const float4*)&sm.Pf[w][rg*8 + prow][half*32 + pcol];
                *(float4*)&attn[(bN + qbase + w*16 + rg*8 + prow) * N_
                                + kbase + t*64 + half*32 + pcol] = pv;
            }

        // P A-frags from Pf
        FragU pa0, pa1;
        {
            float4 p0 = *(const float4*)&sm.Pf[w][lm][q8];
            float4 p1 = *(const float4*)&sm.Pf[w][lm][q8 + 4];
            float4 p2 = *(const float4*)&sm.Pf[w][lm][32 + q8];
            float4 p3 = *(const float4*)&sm.Pf[w][lm][36 + q8];
            #pragma unroll
            for (int j = 0; j < 4; ++j) {
                pa0.us[j]   = f2bf(p0[j]);  pa0.us[4+j] = f2bf(p1[j]);
                pa1.us[j]   = f2bf(p2[j]);  pa1.us[4+j] = f2bf(p3[j]);
            }
        }

        // PV accumulate (Vt read un-swizzles: key block q8 ^ (dg<<3))
        #pragma unroll
        for (int dg = 0; dg < 4; ++dg) {
            const int kb = q8 ^ (dg << 3);
            frag8 v0 = *(const frag8*)&sm.Vt[dg*16 + lm][kb];
            frag8 v1 = *(const frag8*)&sm.Vt[dg*16 + lm][32 + kb];
            oacc[dg] = __builtin_amdgcn_mfma_f32_16x16x32_bf16(pa0.fr, v0, oacc[dg], 0, 0, 0);
            oacc[dg] = __builtin_amdgcn_mfma_f32_16x16x32_bf16(pa1.fr, v1, oacc[dg], 0, 0, 0);
        }
    }

    // partial O -> global (out zeroed before launch; two khalf blocks add)
    #pragma unroll
    for (int dg = 0; dg < 4; ++dg)
        #pragma unroll
        for (int r = 0; r < 4; ++r)
            atomicAdd(&out[(bN + qbase + w*16 + quad*4 + r) * D_ + dg*16 + lm],
                      oacc[dg][r]);
}

extern "C" void kernel_launch(void* const* d_in, const int* in_sizes, int n_in,
                              void* d_out, int out_size, void* d_ws, size_t ws_size,
                              hipStream_t stream) {
    const float* Q = (const float*)d_in[0];
    const float* K = (const float*)d_in[1];
    const float* V = (const float*)d_in[2];
    float* out  = (float*)d_out;
    float* attn = out + (size_t)B_ * N_ * D_;   // tuple order: out, attn_weights
    float* ws   = (float*)d_ws;                 // denominators [B][N] (131 KB)

    hipMemsetAsync(ws, 0, (size_t)B_ * N_ * sizeof(float), stream);
    hipMemsetAsync(out, 0, (size_t)B_ * N_ * D_ * sizeof(float), stream);
    denom_kernel<<<dim3(2048), 256, 0, stream>>>(Q, K, ws);
    attn_kernel <<<dim3(1024), 256, 0, stream>>>(Q, K, V, ws, out, attn);
}

// Round 6
// 363.133 us; speedup vs baseline: 1.1996x; 1.0085x over previous
//
#include <hip/hip_runtime.h>
#include <hip/hip_bf16.h>

// B=16, N=2048, D=64 scaled-dot-product attention, fp32 in/out.
// Outputs concatenated: out [B,N,D] then attn_weights [B,N,N].
//
// R6 = R5 + (a) NONTEMPORAL attn stores: the 268MB attn stream was flowing
// through the 4MB per-XCD L2, evicting the K/V working set the XCD swizzle
// had made resident -> staging loads re-missed to HBM every tile. nt stores
// bypass L2 allocation, keeping K/V L2-hot.  (b) s_setprio(1) around MFMA
// clusters (independent blocks per CU at different phases -> T5 applies).
// All else byte-identical to R5 for clean attribution.
#define B_  16
#define N_  2048
#define D_  64
// scale * log2(e) = (1/8) * 1.4426950408889634
#define SCALE_LOG2 0.18033688011112042f

typedef __attribute__((ext_vector_type(8))) short  frag8;   // 8 bf16 (4 VGPRs)
typedef __attribute__((ext_vector_type(4))) float  floatx4; // 4 fp32 acc

union FragU { frag8 fr; unsigned short us[8]; };

__device__ __forceinline__ unsigned short f2bf(float f) {
    // native cast: compiler packs pairs into v_cvt_pk_bf16_f32
    return __builtin_bit_cast(unsigned short, __float2bfloat16(f));
}
__device__ __forceinline__ float exp2fast(float x) {
    return __builtin_amdgcn_exp2f(x);   // args O(+-30), safe
}

// ======================= kernel A: denominators ==========================
// grid 2048 = 8 xcd * (2 b * 32 qtile * 4 kquarter). Each block: 64 Q rows
// x 512 keys, partial exp-sums -> atomicAdd ws[b][row].
__global__ __launch_bounds__(256) void denom_kernel(
    const float* __restrict__ Q, const float* __restrict__ K,
    float* __restrict__ ws)
{
    __shared__ unsigned short Ks[64][72];

    const int id    = blockIdx.x;
    const int xcd   = id & 7;
    const int s     = id >> 3;            // 0..255
    const int b     = xcd * 2 + (s >> 7); // xcd owns batches {2x, 2x+1}
    const int rem   = s & 127;
    const int qtile = rem >> 2;           // 0..31
    const int kq    = rem & 3;            // 0..3
    const int qbase = qtile * 64;
    const int kbase = kq * 512;
    const size_t bN = (size_t)b * N_;

    const int tid  = threadIdx.x;
    const int w    = tid >> 6;
    const int lane = tid & 63;
    const int lm   = lane & 15;
    const int quad = lane >> 4;
    const int q8   = quad * 8;
    const int srow = tid >> 2;
    const int sc0  = (tid & 3) * 16;

    // Q frags: wave-private rows, direct global->reg
    FragU aq0, aq1;
    {
        const float* qp = Q + (bN + qbase + w*16 + lm) * D_;
        float4 f0 = *(const float4*)(qp + q8);
        float4 f1 = *(const float4*)(qp + q8 + 4);
        float4 f2 = *(const float4*)(qp + 32 + q8);
        float4 f3 = *(const float4*)(qp + 36 + q8);
        #pragma unroll
        for (int j = 0; j < 4; ++j) {
            aq0.us[j]   = f2bf(f0[j]);  aq0.us[4+j] = f2bf(f1[j]);
            aq1.us[j]   = f2bf(f2[j]);  aq1.us[4+j] = f2bf(f3[j]);
        }
    }

    float s4[4] = {0.f, 0.f, 0.f, 0.f};

    ushort4 kreg[4];
    {
        const float4* src = (const float4*)(K + (bN + kbase + srow) * D_ + sc0);
        #pragma unroll
        for (int i = 0; i < 4; ++i) {
            float4 f = src[i];
            kreg[i].x=f2bf(f.x); kreg[i].y=f2bf(f.y);
            kreg[i].z=f2bf(f.z); kreg[i].w=f2bf(f.w);
        }
    }

    for (int t = 0; t < 8; ++t) {          // 8 tiles x 64 keys = 512
        __syncthreads();
        #pragma unroll
        for (int i = 0; i < 4; ++i)
            *(ushort4*)&Ks[srow][sc0 + i*4] = kreg[i];
        __syncthreads();

        float4 fnext[4];
        if (t + 1 < 8) {
            const float4* src = (const float4*)(K + (bN + kbase + (t+1)*64 + srow) * D_ + sc0);
            #pragma unroll
            for (int i = 0; i < 4; ++i) fnext[i] = src[i];
        }

        __builtin_amdgcn_s_setprio(1);
        #pragma unroll
        for (int ns = 0; ns < 4; ++ns) {
            frag8 b0 = *(const frag8*)&Ks[ns*16 + lm][q8];
            frag8 b1 = *(const frag8*)&Ks[ns*16 + lm][32 + q8];
            floatx4 a = {0.f, 0.f, 0.f, 0.f};
            a = __builtin_amdgcn_mfma_f32_16x16x32_bf16(aq0.fr, b0, a, 0, 0, 0);
            a = __builtin_amdgcn_mfma_f32_16x16x32_bf16(aq1.fr, b1, a, 0, 0, 0);
            #pragma unroll
            for (int r = 0; r < 4; ++r)
                s4[r] += exp2fast(a[r] * SCALE_LOG2);
        }
        __builtin_amdgcn_s_setprio(0);

        if (t + 1 < 8) {
            #pragma unroll
            for (int i = 0; i < 4; ++i) {
                kreg[i].x=f2bf(fnext[i].x); kreg[i].y=f2bf(fnext[i].y);
                kreg[i].z=f2bf(fnext[i].z); kreg[i].w=f2bf(fnext[i].w);
            }
        }
    }

    // reduce over the 16 lm lanes, then one atomic per (quad,row)
    #pragma unroll
    for (int r = 0; r < 4; ++r) {
        float v = s4[r];
        #pragma unroll
        for (int off = 1; off < 16; off <<= 1)
            v += __shfl_xor(v, off, 64);
        if (lm == 0)
            atomicAdd(&ws[bN + qbase + w*16 + quad*4 + r], v);
    }
}

// ======================= kernel B: attn + O ==============================
// grid 1024 = 8 xcd * (2 b * 32 qtile * 2 khalf). Each block: 64 Q rows x
// 1024 keys (16 tiles). LDS 35.8KB -> 4 blocks/CU -> 16 waves/CU.
struct __align__(16) SMemB {
    unsigned short Ks[64][72];   // K tile bf16
    unsigned short Vt[64][72];   // V^T tile bf16 [dim][key ^ swz]
    float          Pf[4][16][68];// per-wave normalized P fp32
};

__global__ __launch_bounds__(256, 4) void attn_kernel(
    const float* __restrict__ Q, const float* __restrict__ K,
    const float* __restrict__ V, const float* __restrict__ ws,
    float* __restrict__ out, float* __restrict__ attn)
{
    __shared__ SMemB sm;

    const int id    = blockIdx.x;
    const int xcd   = id & 7;
    const int s     = id >> 3;            // 0..127
    const int b     = xcd * 2 + (s >> 6);
    const int rem   = s & 63;
    const int qtile = rem >> 1;           // 0..31
    const int kh    = rem & 1;            // key half
    const int qbase = qtile * 64;
    const int kbase = kh * 1024;
    const size_t bN = (size_t)b * N_;

    const int tid  = threadIdx.x;
    const int w    = tid >> 6;
    const int lane = tid & 63;
    const int lm   = lane & 15;
    const int quad = lane >> 4;
    const int q8   = quad * 8;
    const int srow = tid >> 2;
    const int sc0  = (tid & 3) * 16;
    const int vswz = srow ^ (((sc0 >> 4) & 3) << 3);   // Vt bank swizzle

    // Q frags
    FragU aq0, aq1;
    {
        const float* qp = Q + (bN + qbase + w*16 + lm) * D_;
        float4 f0 = *(const float4*)(qp + q8);
        float4 f1 = *(const float4*)(qp + q8 + 4);
        float4 f2 = *(const float4*)(qp + 32 + q8);
        float4 f3 = *(const float4*)(qp + 36 + q8);
        #pragma unroll
        for (int j = 0; j < 4; ++j) {
            aq0.us[j]   = f2bf(f0[j]);  aq0.us[4+j] = f2bf(f1[j]);
            aq1.us[j]   = f2bf(f2[j]);  aq1.us[4+j] = f2bf(f3[j]);
        }
    }

    // denominators (complete: kernel A finished before we launched)
    float invl[4];
    #pragma unroll
    for (int r = 0; r < 4; ++r)
        invl[r] = 1.0f / ws[bN + qbase + w*16 + quad*4 + r];

    floatx4 oacc[4];
    #pragma unroll
    for (int dg = 0; dg < 4; ++dg) oacc[dg] = (floatx4){0.f, 0.f, 0.f, 0.f};

    const int prow = lane >> 3;        // attn store: 8 rows x 128B
    const int pcol = (lane & 7) * 4;

    float4 fk[4], fv[4];
    auto loadS = [&](int t) {
        const float4* srcK = (const float4*)(K + (bN + kbase + t*64 + srow) * D_ + sc0);
        const float4* srcV = (const float4*)(V + (bN + kbase + t*64 + srow) * D_ + sc0);
        #pragma unroll
        for (int i = 0; i < 4; ++i) fk[i] = srcK[i];
        #pragma unroll
        for (int i = 0; i < 4; ++i) fv[i] = srcV[i];
    };

    loadS(0);
    for (int t = 0; t < 16; ++t) {
        __syncthreads();   // previous tile consumed
        #pragma unroll
        for (int i = 0; i < 4; ++i) {
            ushort4 u; u.x=f2bf(fk[i].x); u.y=f2bf(fk[i].y);
                       u.z=f2bf(fk[i].z); u.w=f2bf(fk[i].w);
            *(ushort4*)&sm.Ks[srow][sc0 + i*4] = u;
        }
        #pragma unroll
        for (int i = 0; i < 4; ++i) {   // V transposed: Vt[dim][key^swz]
            sm.Vt[sc0 + i*4 + 0][vswz] = f2bf(fv[i].x);
            sm.Vt[sc0 + i*4 + 1][vswz] = f2bf(fv[i].y);
            sm.Vt[sc0 + i*4 + 2][vswz] = f2bf(fv[i].z);
            sm.Vt[sc0 + i*4 + 3][vswz] = f2bf(fv[i].w);
        }
        __syncthreads();   // tile t visible

        if (t + 1 < 16) loadS(t + 1);   // in flight under compute

        // QK^T
        floatx4 acc[4];
        __builtin_amdgcn_s_setprio(1);
        #pragma unroll
        for (int ns = 0; ns < 4; ++ns) {
            frag8 b0 = *(const frag8*)&sm.Ks[ns*16 + lm][q8];
            frag8 b1 = *(const frag8*)&sm.Ks[ns*16 + lm][32 + q8];
            floatx4 a = {0.f, 0.f, 0.f, 0.f};
            a = __builtin_amdgcn_mfma_f32_16x16x32_bf16(aq0.fr, b0, a, 0, 0, 0);
            a = __builtin_amdgcn_mfma_f32_16x16x32_bf16(aq1.fr, b1, a, 0, 0, 0);
            acc[ns] = a;
        }
        __builtin_amdgcn_s_setprio(0);

        // normalized P -> wave-private fp32 LDS
        #pragma unroll
        for (int ns = 0; ns < 4; ++ns)
            #pragma unroll
            for (int r = 0; r < 4; ++r)
                sm.Pf[w][quad*4 + r][ns*16 + lm] =
                    exp2fast(acc[ns][r] * SCALE_LOG2) * invl[r];

        // attn: 4 x 128B-contiguous NONTEMPORAL float4 stores per wave-tile
        // (nt: no L2 allocation for the 268MB one-time stream -> K/V stay
        // L2-resident; in-wave LDS write->read ordering, no barrier needed)
        #pragma unroll
        for (int rg = 0; rg < 2; ++rg)
            #pragma unroll
            for (int half = 0; half < 2; ++half) {
                floatx4 pv = *(const floatx4*)&sm.Pf[w][rg*8 + prow][half*32 + pcol];
                __builtin_nontemporal_store(pv,
                    (floatx4*)&attn[(bN + qbase + w*16 + rg*8 + prow) * N_
                                    + kbase + t*64 + half*32 + pcol]);
            }

        // P A-frags from Pf
        FragU pa0, pa1;
        {
            float4 p0 = *(const float4*)&sm.Pf[w][lm][q8];
            float4 p1 = *(const float4*)&sm.Pf[w][lm][q8 + 4];
            float4 p2 = *(const float4*)&sm.Pf[w][lm][32 + q8];
            float4 p3 = *(const float4*)&sm.Pf[w][lm][36 + q8];
            #pragma unroll
            for (int j = 0; j < 4; ++j) {
                pa0.us[j]   = f2bf(p0[j]);  pa0.us[4+j] = f2bf(p1[j]);
                pa1.us[j]   = f2bf(p2[j]);  pa1.us[4+j] = f2bf(p3[j]);
            }
        }

        // PV accumulate (Vt read un-swizzles: key block q8 ^ (dg<<3))
        __builtin_amdgcn_s_setprio(1);
        #pragma unroll
        for (int dg = 0; dg < 4; ++dg) {
            const int kb = q8 ^ (dg << 3);
            frag8 v0 = *(const frag8*)&sm.Vt[dg*16 + lm][kb];
            frag8 v1 = *(const frag8*)&sm.Vt[dg*16 + lm][32 + kb];
            oacc[dg] = __builtin_amdgcn_mfma_f32_16x16x32_bf16(pa0.fr, v0, oacc[dg], 0, 0, 0);
            oacc[dg] = __builtin_amdgcn_mfma_f32_16x16x32_bf16(pa1.fr, v1, oacc[dg], 0, 0, 0);
        }
        __builtin_amdgcn_s_setprio(0);
    }

    // partial O -> global (out zeroed before launch; two khalf blocks add)
    #pragma unroll
    for (int dg = 0; dg < 4; ++dg)
        #pragma unroll
        for (int r = 0; r < 4; ++r)
            atomicAdd(&out[(bN + qbase + w*16 + quad*4 + r) * D_ + dg*16 + lm],
                      oacc[dg][r]);
}

extern "C" void kernel_launch(void* const* d_in, const int* in_sizes, int n_in,
                              void* d_out, int out_size, void* d_ws, size_t ws_size,
                              hipStream_t stream) {
    const float* Q = (const float*)d_in[0];
    const float* K = (const float*)d_in[1];
    const float* V = (const float*)d_in[2];
    float* out  = (float*)d_out;
    float* attn = out + (size_t)B_ * N_ * D_;   // tuple order: out, attn_weights
    float* ws   = (float*)d_ws;                 // denominators [B][N] (131 KB)

    hipMemsetAsync(ws, 0, (size_t)B_ * N_ * sizeof(float), stream);
    hipMemsetAsync(out, 0, (size_t)B_ * N_ * D_ * sizeof(float), stream);
    denom_kernel<<<dim3(2048), 256, 0, stream>>>(Q, K, ws);
    attn_kernel <<<dim3(1024), 256, 0, stream>>>(Q, K, V, ws, out, attn);
}